// Round 2
// baseline (10046.647 us; speedup 1.0000x reference)
//
#include <hip/hip_runtime.h>
#include <cstdint>
#include <cstddef>
#include <type_traits>

// ---------------------------------------------------------------------------
// VQ-VAE forward (B=2048, L=100, D=64, K=64, CB=512).
// Encoder convs + codebook distance in f64 accumulation (argmin must match
// the f64 numpy reference bit-for-bit on index decisions); decoder in f32.
// ---------------------------------------------------------------------------

constexpr int B  = 2048;
constexpr int L  = 100;
constexpr int D  = 64;
constexpr int K  = 64;
constexpr int CB = 512;

// workspace layout (float offsets), with region reuse:
//  R0: A1 [B*81*128=21233664] -> XENC [B*49*512=51380224] -> G2 [B*81*128]
//  R1: A2 [B*64*256=33554432] -> G1 [B*64*256]
constexpr size_t R0_OFF  = 0;
constexpr size_t R0_SZ   = 51380224;
constexpr size_t R1_OFF  = R0_OFF + R0_SZ;
constexpr size_t R1_SZ   = 33554432;
constexpr size_t IDX_OFF = R1_OFF + R1_SZ;     // 2048*49 ints
constexpr size_t UBT_OFF = IDX_OFF + 100352;   // 512*64 transposed codebook (f32)
constexpr size_t CBN_OFF = UBT_OFF + 32768;    // 64 code norms (f64 -> 128 floats)
constexpr size_t ACC_OFF = CBN_OFF + 128;      // 2 loss accumulators (f32)

__device__ inline float  fmah(float a, float b, float c)   { return fmaf(a, b, c); }
__device__ inline double fmah(double a, double b, double c){ return fma(a, b, c); }

// ---------------------------------------------------------------------------
// Generic 2x2 conv, one sample per block, 256 threads.
// MODE 0: read [B,IH,IW,IC] from `in`
// MODE 1: gather from embedding table via ids, * mask   (conv1 input)
// MODE 2: gather codebook rows via qidx                 (deconv1 input)
// DACC:   accumulate in double (encoder path -> exact argmin)
// ---------------------------------------------------------------------------
template<int IH, int IW, int IC, int OC, int PAD, int MODE, bool BN, bool DACC>
__global__ __launch_bounds__(256)
void conv2x2_k(const float* __restrict__ in,
               const int*   __restrict__ ids,
               const int*   __restrict__ masks,
               const float* __restrict__ table,
               const int*   __restrict__ qidx,
               const float* __restrict__ book,
               const float* __restrict__ w,      // [2,2,IC,OC]
               const float* __restrict__ bias,   // [OC]
               const float* __restrict__ gamma,  // [OC] (BN)
               const float* __restrict__ beta,   // [OC] (BN)
               float* __restrict__ out)          // [B,OH,OW,OC]
{
    using accT = typename std::conditional<DACC, double, float>::type;

    constexpr int OH   = IH + 2 * PAD - 1;
    constexpr int OW   = IW + 2 * PAD - 1;
    constexpr int NPOS = OH * OW;
    constexpr int INSZ = IH * IW * IC;
    const int b = blockIdx.x;

    __shared__ float s_in[INSZ];

    if constexpr (MODE == 0) {
        const float4* src = (const float4*)(in + (size_t)b * INSZ);
        float4* dst = (float4*)s_in;
        for (int i = threadIdx.x; i < INSZ / 4; i += 256) dst[i] = src[i];
    } else if constexpr (MODE == 1) {
        for (int i = threadIdx.x; i < INSZ; i += 256) {
            int l = i >> 6, d = i & 63;           // IC == 64
            int id = ids[b * L + l];
            float m = (masks[b * L + l] >= 1) ? 1.f : 0.f;
            s_in[i] = table[(size_t)id * 64 + d] * m;
        }
    } else {
        for (int i = threadIdx.x; i < INSZ; i += 256) {
            int p = i >> 9, c = i & 511;          // IC == 512
            int kq = qidx[b * 49 + p];
            s_in[i] = book[kq * 512 + c];
        }
    }
    __syncthreads();

    constexpr int PG = (NPOS + 3) / 4;
    constexpr int OG = OC / 4;
    constexpr int ITEMS = PG * OG;
    const accT rs = (accT)(1.0 / sqrt(1.0 + 1e-3));   // BN scale

    for (int item = threadIdx.x; item < ITEMS; item += 256) {
        const int pg  = item / OG;
        const int og  = item - pg * OG;
        const int oc0 = og * 4;

        accT acc[4][4] = {};

        #pragma unroll
        for (int kk = 0; kk < 4; ++kk) {
            const int ky = kk >> 1, kx = kk & 1;
            const float* wk = w + (size_t)(kk * IC) * OC + oc0;
            int base[4]; accT vm[4];
            #pragma unroll
            for (int pp = 0; pp < 4; ++pp) {
                int p = pg * 4 + pp;
                int valid = (p < NPOS) ? 1 : 0;
                p = valid ? p : 0;
                int y = p / OW + ky - PAD;
                int x = p % OW + kx - PAD;
                valid &= (y >= 0) & (y < IH) & (x >= 0) & (x < IW);
                base[pp] = valid ? (y * IW + x) * IC : 0;
                vm[pp]   = valid ? (accT)1 : (accT)0;
            }
            for (int ic = 0; ic < IC; ++ic) {
                const float4 wv = *(const float4*)(wk + (size_t)ic * OC);
                const accT w0 = (accT)wv.x, w1 = (accT)wv.y, w2 = (accT)wv.z, w3 = (accT)wv.w;
                #pragma unroll
                for (int pp = 0; pp < 4; ++pp) {
                    accT a = (accT)s_in[base[pp] + ic] * vm[pp];
                    acc[pp][0] = fmah(a, w0, acc[pp][0]);
                    acc[pp][1] = fmah(a, w1, acc[pp][1]);
                    acc[pp][2] = fmah(a, w2, acc[pp][2]);
                    acc[pp][3] = fmah(a, w3, acc[pp][3]);
                }
            }
        }

        #pragma unroll
        for (int pp = 0; pp < 4; ++pp) {
            int p = pg * 4 + pp;
            if (p >= NPOS) break;
            float4 v4;
            float* vv = (float*)&v4;
            #pragma unroll
            for (int oo = 0; oo < 4; ++oo) {
                accT v = acc[pp][oo] + (accT)bias[oc0 + oo];
                if constexpr (BN) {
                    v = v * ((accT)gamma[oc0 + oo] * rs) + (accT)beta[oc0 + oo];
                    v = v > (accT)0 ? v : (accT)0;
                }
                vv[oo] = (float)v;
            }
            *(float4*)(out + ((size_t)b * NPOS + p) * OC + oc0) = v4;
        }
    }
}

// ---------------------------------------------------------------------------
// prep: transpose codebook to [c][k], f64 code norms, zero loss accumulators
// ---------------------------------------------------------------------------
__global__ __launch_bounds__(256)
void prep_k(const float* __restrict__ book, float* __restrict__ ubt,
            double* __restrict__ cbn, float* __restrict__ acc)
{
    for (int i = threadIdx.x; i < K * CB; i += 256) {
        int k = i >> 9, c = i & 511;
        ubt[c * 64 + k] = book[i];
    }
    if (threadIdx.x < 64) {
        const float* r = book + threadIdx.x * 512;
        double s = 0.0;
        for (int c = 0; c < 512; ++c) { double v = (double)r[c]; s = fma(v, v, s); }
        cbn[threadIdx.x] = s;
    }
    if (threadIdx.x < 2) acc[threadIdx.x] = 0.f;
}

// ---------------------------------------------------------------------------
// NN codebook search: wave per 4 rows, lane = code, all math in f64.
// dist = ||c||^2 - 2 x.c   (||x||^2 constant per row, dropped)
// Tie -> lowest index (numpy argmin). loss2 accumulated here.
// ---------------------------------------------------------------------------
__global__ __launch_bounds__(256)
void nn_k(const float* __restrict__ xenc, const float* __restrict__ ubt,
          const double* __restrict__ cbn, int* __restrict__ qidx,
          float* __restrict__ acc, const float* __restrict__ book)
{
    const int lane = threadIdx.x & 63;
    const int wave = threadIdx.x >> 6;
    const int wid  = blockIdx.x * 4 + wave;   // 25088 waves
    const int row0 = wid * 4;
    const float* x0 = xenc + (size_t)row0 * 512;

    double dot[4] = {0.0, 0.0, 0.0, 0.0};
    for (int c = 0; c < 512; ++c) {
        double ub = (double)ubt[c * 64 + lane];        // coalesced
        dot[0] = fma((double)x0[c],        ub, dot[0]);
        dot[1] = fma((double)x0[512 + c],  ub, dot[1]);
        dot[2] = fma((double)x0[1024 + c], ub, dot[2]);
        dot[3] = fma((double)x0[1536 + c], ub, dot[3]);
    }

    float l2 = 0.f;
    #pragma unroll
    for (int j = 0; j < 4; ++j) {
        double dmin = cbn[lane] - 2.0 * dot[j];
        int kk = lane;
        #pragma unroll
        for (int off = 32; off > 0; off >>= 1) {
            double od = __shfl_xor(dmin, off);
            int    ok = __shfl_xor(kk, off);
            if (od < dmin || (od == dmin && ok < kk)) { dmin = od; kk = ok; }
        }
        if (lane == 0) qidx[row0 + j] = kk;
        const float* xr = x0 + j * 512;
        const float* cr = book + kk * 512;
        float s = 0.f;
        for (int c = lane; c < 512; c += 64) {
            float dff = cr[c] - xr[c];
            s = fmaf(dff, dff, s);
        }
        l2 += s;
    }
    #pragma unroll
    for (int off = 32; off > 0; off >>= 1) l2 += __shfl_xor(l2, off);
    if (lane == 0) atomicAdd(acc + 1, l2);
}

// ---------------------------------------------------------------------------
// finalize: loss1 = sum (hist - vq_x)^2 (hist re-gathered), vq_mean
// ---------------------------------------------------------------------------
__global__ __launch_bounds__(256)
void finalize_k(const float* __restrict__ vqx, const int* __restrict__ ids,
                const int* __restrict__ masks, const float* __restrict__ table,
                float* __restrict__ out_mean, float* __restrict__ acc)
{
    const int b = blockIdx.x;
    const int tid = threadIdx.x;
    const float* vb = vqx + (size_t)b * (L * D);

    float part = 0.f;
    for (int i = tid; i < L * D; i += 256) {
        int l = i >> 6, d = i & 63;
        int id = ids[b * L + l];
        float m = (masks[b * L + l] >= 1) ? 1.f : 0.f;
        float h = table[(size_t)id * 64 + d] * m;
        float diff = h - vb[i];
        part = fmaf(diff, diff, part);
    }
    __shared__ float s_red[4];
    #pragma unroll
    for (int off = 32; off > 0; off >>= 1) part += __shfl_down(part, off);
    if ((tid & 63) == 0) s_red[tid >> 6] = part;
    __syncthreads();
    if (tid == 0) atomicAdd(acc + 0, s_red[0] + s_red[1] + s_red[2] + s_red[3]);

    if (tid < 64) {
        float msum = 0.f;
        for (int l = 0; l < L; ++l) msum += (masks[b * L + l] >= 1) ? 1.f : 0.f;
        float s = 0.f;
        for (int l = 0; l < L; ++l) s += vb[l * 64 + tid];
        out_mean[b * 64 + tid] = s / msum;
    }
}

__global__ void loss_k(const float* __restrict__ acc, float* __restrict__ out_loss)
{
    float l1 = acc[0] / 13107200.f;     // mse(hist, vq_x)
    float l2 = acc[1] / 51380224.f;     // mse(quantized, x_encode)
    out_loss[0] = l1 + l2 + 0.25f * l2; // + beta * mse(x_encode, quantized)
}

// ---------------------------------------------------------------------------
extern "C" void kernel_launch(void* const* d_in, const int* in_sizes, int n_in,
                              void* d_out, int out_size, void* d_ws, size_t ws_size,
                              hipStream_t stream)
{
    const int*   ids   = (const int*)d_in[0];
    const int*   masks = (const int*)d_in[1];
    const float* table = (const float*)d_in[2];
    const float* book  = (const float*)d_in[3];
    const float* e_w1  = (const float*)d_in[4];
    const float* e_b1  = (const float*)d_in[5];
    const float* e_g1  = (const float*)d_in[6];
    const float* e_be1 = (const float*)d_in[7];
    const float* e_w2  = (const float*)d_in[8];
    const float* e_b2  = (const float*)d_in[9];
    const float* e_g2  = (const float*)d_in[10];
    const float* e_be2 = (const float*)d_in[11];
    const float* e_w3  = (const float*)d_in[12];
    const float* e_b3  = (const float*)d_in[13];
    const float* d_w1  = (const float*)d_in[14];
    const float* d_b1  = (const float*)d_in[15];
    const float* d_g1  = (const float*)d_in[16];
    const float* d_be1 = (const float*)d_in[17];
    const float* d_w2  = (const float*)d_in[18];
    const float* d_b2  = (const float*)d_in[19];
    const float* d_g2  = (const float*)d_in[20];
    const float* d_be2 = (const float*)d_in[21];
    const float* d_w3  = (const float*)d_in[22];
    const float* d_b3  = (const float*)d_in[23];

    float* ws  = (float*)d_ws;
    float*  A1  = ws + R0_OFF;            // [B,9,9,128]
    float*  A2  = ws + R1_OFF;            // [B,8,8,256]
    float*  XE  = ws + R0_OFF;            // [B,7,7,512]  (overwrites dead A1)
    float*  G1  = ws + R1_OFF;            // [B,8,8,256]  (overwrites dead A2)
    float*  G2  = ws + R0_OFF;            // [B,9,9,128]  (overwrites dead XENC)
    int*    IDX = (int*)(ws + IDX_OFF);
    float*  UBT = ws + UBT_OFF;
    double* CBN = (double*)(ws + CBN_OFF);
    float*  ACC = ws + ACC_OFF;

    float* out_mean = (float*)d_out;
    float* out_vqx  = (float*)d_out + (size_t)B * 64;
    float* out_loss = (float*)d_out + (size_t)B * 64 + (size_t)B * L * D;

    prep_k<<<1, 256, 0, stream>>>(book, UBT, CBN, ACC);

    // encoder (f64 accumulation -> exact x_encode for argmin)
    conv2x2_k<10,10, 64,128,0,1,true ,true ><<<B,256,0,stream>>>(nullptr, ids, masks, table, nullptr, nullptr, e_w1, e_b1, e_g1, e_be1, A1);
    conv2x2_k< 9, 9,128,256,0,0,true ,true ><<<B,256,0,stream>>>(A1, nullptr, nullptr, nullptr, nullptr, nullptr, e_w2, e_b2, e_g2, e_be2, A2);
    conv2x2_k< 8, 8,256,512,0,0,false,true ><<<B,256,0,stream>>>(A2, nullptr, nullptr, nullptr, nullptr, nullptr, e_w3, e_b3, nullptr, nullptr, XE);

    // codebook nearest neighbor (f64 dist) + loss2
    nn_k<<<6272, 256, 0, stream>>>(XE, UBT, CBN, IDX, ACC, book);

    // decoder f32 (conv_transpose == conv with pad=1, unflipped kernel)
    conv2x2_k< 7, 7,512,256,1,2,true ,false><<<B,256,0,stream>>>(nullptr, nullptr, nullptr, nullptr, IDX, book, d_w1, d_b1, d_g1, d_be1, G1);
    conv2x2_k< 8, 8,256,128,1,0,true ,false><<<B,256,0,stream>>>(G1, nullptr, nullptr, nullptr, nullptr, nullptr, d_w2, d_b2, d_g2, d_be2, G2);
    conv2x2_k< 9, 9,128, 64,1,0,false,false><<<B,256,0,stream>>>(G2, nullptr, nullptr, nullptr, nullptr, nullptr, d_w3, d_b3, nullptr, nullptr, out_vqx);

    // vq_mean + loss1, then scalar loss
    finalize_k<<<B, 256, 0, stream>>>(out_vqx, ids, masks, table, out_mean, ACC);
    loss_k<<<1, 1, 0, stream>>>(ACC, out_loss);
}

// Round 3
// 6995.800 us; speedup vs baseline: 1.4361x; 1.4361x over previous
//
#include <hip/hip_runtime.h>
#include <cstdint>
#include <cstddef>

// ---------------------------------------------------------------------------
// VQ-VAE forward (B=2048, L=100, D=64, K=64, CB=512).
// All convs f32. Argmin exactness vs the f64 numpy reference is guaranteed by
// margin flagging: rows whose best-vs-2nd distance gap <= MARGIN get their
// entire encoder receptive field recomputed in f64 (few % of rows).
// ---------------------------------------------------------------------------

constexpr int B  = 2048;
constexpr int L  = 100;
constexpr int K  = 64;
constexpr int CB = 512;
#define MARGIN 0.05f

// workspace layout (float offsets), with region reuse:
//  R0: A1 [B*81*128] -> XENC [B*49*512] -> G2 [B*81*128]
//  R1: A2 [B*64*256] -> G1 [B*64*256]
constexpr size_t R0_OFF  = 0;
constexpr size_t R0_SZ   = 51380224;
constexpr size_t R1_OFF  = R0_OFF + R0_SZ;
constexpr size_t R1_SZ   = 33554432;
constexpr size_t IDX_OFF = R1_OFF + R1_SZ;     // 2048*49 ints
constexpr size_t UBT_OFF = IDX_OFF + 100352;   // 512*64 transposed codebook
constexpr size_t CBN_OFF = UBT_OFF + 32768;    // 64 code norms (f32)
constexpr size_t CNT_OFF = CBN_OFF + 64;       // 1 int worklist count
constexpr size_t ACC_OFF = CNT_OFF + 1;        // 2 loss accumulators
constexpr size_t WL_OFF  = ACC_OFF + 2;        // up to 100352 ints

// ---------------------------------------------------------------------------
// f32 conv 2x2 (VALID, or pad=1 unflipped for conv_transpose).
// One (sample, oc-split) per block, 256 threads, IC chunked through LDS.
// Register tile: POSJ positions x 4 output channels per item.
// MODE 0: read [B,IH,IW,IC];  MODE 1: gather+mask (conv1);  MODE 2: codebook
// rows via qidx (deconv1).
// ---------------------------------------------------------------------------
template<int IH,int IW,int IC,int OC,int PAD,int MODE,bool BN_,
         int POSJ,int OCSPLIT,int ICC>
__global__ __launch_bounds__(256)
void convf_k(const float* __restrict__ in,
             const int*   __restrict__ ids,
             const int*   __restrict__ masks,
             const float* __restrict__ table,
             const int*   __restrict__ qidx,
             const float* __restrict__ book,
             const float* __restrict__ w,      // [2,2,IC,OC]
             const float* __restrict__ bias,
             const float* __restrict__ gamma,
             const float* __restrict__ beta,
             float* __restrict__ out)          // [B,OH,OW,OC]
{
    constexpr int OH = IH + 2*PAD - 1, OW = IW + 2*PAD - 1;
    constexpr int NPOS = OH*OW, IHW = IH*IW;
    constexpr int OCB = OC/OCSPLIT;
    constexpr int PG  = (NPOS + POSJ - 1)/POSJ;
    constexpr int OG  = OCB/4;
    constexpr int ITEMS = PG*OG;
    constexpr int ITERS = (ITEMS + 255)/256;
    constexpr int NCH = IC/ICC;
    constexpr int ZOFF = IHW*ICC;              // zero slot for invalid taps
    constexpr int C4 = ICC/4;

    const int bx = blockIdx.x;
    const int b  = bx / OCSPLIT;
    const int oc_base = (bx % OCSPLIT) * OCB;
    const int tid = threadIdx.x;

    __shared__ float s_in[(IHW+1)*ICC];

    float acc[ITERS][POSJ][4];
    #pragma unroll
    for (int a = 0; a < ITERS; ++a)
        #pragma unroll
        for (int p = 0; p < POSJ; ++p)
            #pragma unroll
            for (int o = 0; o < 4; ++o) acc[a][p][o] = 0.f;

    for (int ch = 0; ch < NCH; ++ch) {
        const int ic0 = ch*ICC;
        float4* s4 = (float4*)s_in;
        if (tid < C4) s4[IHW*C4 + tid] = make_float4(0.f,0.f,0.f,0.f);
        if constexpr (MODE == 0) {
            for (int i = tid; i < IHW*C4; i += 256) {
                int pos = i / C4, c4 = i - pos*C4;
                const float4* src = (const float4*)(in + ((size_t)b*IHW + pos)*IC + ic0);
                s4[i] = src[c4];
            }
        } else if constexpr (MODE == 1) {
            for (int i = tid; i < IHW*C4; i += 256) {
                int pos = i / C4, c4 = i - pos*C4;
                int id = ids[b*L + pos];
                float m = (masks[b*L + pos] >= 1) ? 1.f : 0.f;
                float4 v = ((const float4*)table)[(size_t)id*16 + c4];
                v.x *= m; v.y *= m; v.z *= m; v.w *= m;
                s4[i] = v;
            }
        } else {
            for (int i = tid; i < IHW*C4; i += 256) {
                int pos = i / C4, c4 = i - pos*C4;
                int kq = qidx[b*49 + pos];
                s4[i] = ((const float4*)book)[(size_t)(kq*512 + ic0)/4 + c4];
            }
        }
        __syncthreads();

        #pragma unroll
        for (int it = 0; it < ITERS; ++it) {
            const int item = tid + it*256;
            if (item < ITEMS) {
                const int pg  = item / OG;
                const int og  = item - pg*OG;
                const int oc0 = oc_base + og*4;
                #pragma unroll
                for (int kk = 0; kk < 4; ++kk) {
                    const int ky = kk >> 1, kx = kk & 1;
                    int base[POSJ];
                    #pragma unroll
                    for (int pp = 0; pp < POSJ; ++pp) {
                        int p = pg*POSJ + pp;
                        bool v = (p < NPOS);
                        p = v ? p : 0;
                        int y = p/OW + ky - PAD;
                        int x = p - (p/OW)*OW + kx - PAD;
                        v = v && (y >= 0) && (y < IH) && (x >= 0) && (x < IW);
                        base[pp] = v ? (y*IW + x)*ICC : ZOFF;
                    }
                    const float* wrow = w + (size_t)(kk*IC + ic0)*OC + oc0;
                    for (int ic = 0; ic < ICC; ic += 4) {
                        float4 w0 = *(const float4*)(wrow + (size_t)(ic+0)*OC);
                        float4 w1 = *(const float4*)(wrow + (size_t)(ic+1)*OC);
                        float4 w2 = *(const float4*)(wrow + (size_t)(ic+2)*OC);
                        float4 w3 = *(const float4*)(wrow + (size_t)(ic+3)*OC);
                        #pragma unroll
                        for (int pp = 0; pp < POSJ; ++pp) {
                            float4 xi = *(const float4*)(s_in + base[pp] + ic);
                            acc[it][pp][0] = fmaf(xi.x, w0.x, fmaf(xi.y, w1.x, fmaf(xi.z, w2.x, fmaf(xi.w, w3.x, acc[it][pp][0]))));
                            acc[it][pp][1] = fmaf(xi.x, w0.y, fmaf(xi.y, w1.y, fmaf(xi.z, w2.y, fmaf(xi.w, w3.y, acc[it][pp][1]))));
                            acc[it][pp][2] = fmaf(xi.x, w0.z, fmaf(xi.y, w1.z, fmaf(xi.z, w2.z, fmaf(xi.w, w3.z, acc[it][pp][2]))));
                            acc[it][pp][3] = fmaf(xi.x, w0.w, fmaf(xi.y, w1.w, fmaf(xi.z, w2.w, fmaf(xi.w, w3.w, acc[it][pp][3]))));
                        }
                    }
                }
            }
        }
        __syncthreads();
    }

    const float rs = (float)(1.0/sqrt(1.0 + 1e-3));
    #pragma unroll
    for (int it = 0; it < ITERS; ++it) {
        const int item = tid + it*256;
        if (item < ITEMS) {
            const int pg  = item / OG;
            const int og  = item - pg*OG;
            const int oc0 = oc_base + og*4;
            float4 bi = *(const float4*)(bias + oc0);
            float4 ga, be;
            if constexpr (BN_) {
                ga = *(const float4*)(gamma + oc0);
                be = *(const float4*)(beta + oc0);
            }
            #pragma unroll
            for (int pp = 0; pp < POSJ; ++pp) {
                int p = pg*POSJ + pp;
                if (p < NPOS) {
                    float4 v;
                    v.x = acc[it][pp][0] + bi.x;
                    v.y = acc[it][pp][1] + bi.y;
                    v.z = acc[it][pp][2] + bi.z;
                    v.w = acc[it][pp][3] + bi.w;
                    if constexpr (BN_) {
                        v.x = fmaxf(fmaf(v.x, ga.x*rs, be.x), 0.f);
                        v.y = fmaxf(fmaf(v.y, ga.y*rs, be.y), 0.f);
                        v.z = fmaxf(fmaf(v.z, ga.z*rs, be.z), 0.f);
                        v.w = fmaxf(fmaf(v.w, ga.w*rs, be.w), 0.f);
                    }
                    *(float4*)(out + ((size_t)b*NPOS + p)*OC + oc0) = v;
                }
            }
        }
    }
}

// ---------------------------------------------------------------------------
// prep: transpose codebook, code norms, zero accumulators + worklist count
// ---------------------------------------------------------------------------
__global__ __launch_bounds__(256)
void prep_k(const float* __restrict__ book, float* __restrict__ ubt,
            float* __restrict__ cbn, float* __restrict__ acc, int* __restrict__ cnt)
{
    for (int i = threadIdx.x; i < K * CB; i += 256) {
        int k = i >> 9, c = i & 511;
        ubt[c * 64 + k] = book[i];
    }
    if (threadIdx.x < 64) {
        const float* r = book + threadIdx.x * 512;
        float s = 0.f;
        for (int c = 0; c < 512; ++c) s = fmaf(r[c], r[c], s);
        cbn[threadIdx.x] = s;
    }
    if (threadIdx.x < 2) acc[threadIdx.x] = 0.f;
    if (threadIdx.x == 0) *cnt = 0;
}

// ---------------------------------------------------------------------------
// NN search (f32): wave per 4 rows, lane = code. Tracks best + runner-up;
// gap <= MARGIN rows go on the worklist for f64 re-verification.
// loss2 = dmin + ||x||^2 accumulated here.
// ---------------------------------------------------------------------------
__global__ __launch_bounds__(256)
void nn_k(const float* __restrict__ xenc, const float* __restrict__ ubt,
          const float* __restrict__ cbn, int* __restrict__ qidx,
          float* __restrict__ acc, int* __restrict__ cnt, int* __restrict__ wl)
{
    const int lane = threadIdx.x & 63;
    const int wave = threadIdx.x >> 6;
    const int wid  = blockIdx.x * 4 + wave;
    const int row0 = wid * 4;
    const float* x0 = xenc + (size_t)row0 * 512;

    float dot[4] = {0.f,0.f,0.f,0.f};
    float xn[4]  = {0.f,0.f,0.f,0.f};
    for (int c = 0; c < 512; ++c) {
        float ub = ubt[c * 64 + lane];
        float a0 = x0[c], a1 = x0[512+c], a2 = x0[1024+c], a3 = x0[1536+c];
        dot[0] = fmaf(a0, ub, dot[0]);  xn[0] = fmaf(a0, a0, xn[0]);
        dot[1] = fmaf(a1, ub, dot[1]);  xn[1] = fmaf(a1, a1, xn[1]);
        dot[2] = fmaf(a2, ub, dot[2]);  xn[2] = fmaf(a2, a2, xn[2]);
        dot[3] = fmaf(a3, ub, dot[3]);  xn[3] = fmaf(a3, a3, xn[3]);
    }

    float l2sum = 0.f;
    #pragma unroll
    for (int j = 0; j < 4; ++j) {
        float d1 = cbn[lane] - 2.f * dot[j];
        int   k1 = lane;
        float d2 = 3.4e38f;
        #pragma unroll
        for (int off = 32; off > 0; off >>= 1) {
            float od1 = __shfl_xor(d1, off);
            int   ok1 = __shfl_xor(k1, off);
            float od2 = __shfl_xor(d2, off);
            if (od1 < d1 || (od1 == d1 && ok1 < k1)) {
                d2 = fminf(d1, od2); d1 = od1; k1 = ok1;
            } else {
                d2 = fminf(d2, od1);
            }
        }
        if (lane == 0) {
            qidx[row0 + j] = k1;
            if (d2 - d1 <= MARGIN) { int t = atomicAdd(cnt, 1); wl[t] = row0 + j; }
            l2sum += d1 + xn[j];
        }
    }
    if (lane == 0) atomicAdd(acc + 1, l2sum);
}

// ---------------------------------------------------------------------------
// f64 re-verification of flagged rows: recompute the row's full encoder
// receptive field (4x4 gather -> 3x3 A1 -> 2x2 A2 -> 512-ch x row) and all
// 64 code distances in f64; overwrite qidx. ~1.4M f64 MAC per row.
// ---------------------------------------------------------------------------
__global__ __launch_bounds__(256)
void recompute_k(const int* __restrict__ wl, const int* __restrict__ cnt,
                 const int* __restrict__ ids, const int* __restrict__ masks,
                 const float* __restrict__ table, const float* __restrict__ book,
                 const float* __restrict__ e_w1, const float* __restrict__ e_b1,
                 const float* __restrict__ e_g1, const float* __restrict__ e_be1,
                 const float* __restrict__ e_w2, const float* __restrict__ e_b2,
                 const float* __restrict__ e_g2, const float* __restrict__ e_be2,
                 const float* __restrict__ e_w3, const float* __restrict__ e_b3,
                 int* __restrict__ qidx)
{
    __shared__ double s_h[16*64];
    __shared__ double s_a1[9*128];
    __shared__ double s_a2[4*256];
    __shared__ double s_x[512];
    __shared__ double s_d[256];

    const int tid = threadIdx.x;
    const double rs = 1.0 / sqrt(1.0 + 1e-3);
    const int n = *cnt;

    for (int wi = blockIdx.x; wi < n; wi += gridDim.x) {
        const int row = wl[wi];
        const int b = row / 49, p = row % 49;
        const int py = p / 7, px = p % 7;

        for (int i = tid; i < 16*64; i += 256) {
            int cell = i >> 6, d = i & 63;
            int l = (py + (cell >> 2)) * 10 + (px + (cell & 3));
            int id = ids[b*100 + l];
            double m = (masks[b*100 + l] >= 1) ? 1.0 : 0.0;
            s_h[i] = (double)table[(size_t)id*64 + d] * m;
        }
        __syncthreads();

        for (int i = tid; i < 9*128; i += 256) {          // A1 3x3 region
            int cell = i >> 7, oc = i & 127;
            int ry = cell / 3, rx = cell % 3;
            double s = 0.0;
            #pragma unroll
            for (int kk = 0; kk < 4; ++kk) {
                int icell = (ry + (kk>>1))*4 + (rx + (kk&1));
                const double* hh = s_h + icell*64;
                const float* ww = e_w1 + (kk*64)*128 + oc;
                for (int ic = 0; ic < 64; ++ic)
                    s = fma(hh[ic], (double)ww[ic*128], s);
            }
            s += (double)e_b1[oc];
            s = s * ((double)e_g1[oc] * rs) + (double)e_be1[oc];
            s_a1[i] = s > 0.0 ? s : 0.0;
        }
        __syncthreads();

        for (int i = tid; i < 4*256; i += 256) {          // A2 2x2 region
            int cell = i >> 8, oc = i & 255;
            int qy = cell >> 1, qx = cell & 1;
            double s = 0.0;
            #pragma unroll
            for (int kk = 0; kk < 4; ++kk) {
                int icell = (qy + (kk>>1))*3 + (qx + (kk&1));
                const double* aa = s_a1 + icell*128;
                const float* ww = e_w2 + (kk*128)*256 + oc;
                for (int ic = 0; ic < 128; ++ic)
                    s = fma(aa[ic], (double)ww[ic*256], s);
            }
            s += (double)e_b2[oc];
            s = s * ((double)e_g2[oc] * rs) + (double)e_be2[oc];
            s_a2[i] = s > 0.0 ? s : 0.0;
        }
        __syncthreads();

        for (int i = tid; i < 512; i += 256) {            // x_encode row
            double s = 0.0;
            #pragma unroll
            for (int kk = 0; kk < 4; ++kk) {
                const double* aa = s_a2 + kk*256;
                const float* ww = e_w3 + (kk*256)*512 + i;
                for (int ic = 0; ic < 256; ++ic)
                    s = fma(aa[ic], (double)ww[ic*512], s);
            }
            s_x[i] = s + (double)e_b3[i];
        }
        __syncthreads();

        {                                                  // distances
            int k = tid & 63, seg = tid >> 6;
            const float* cr = book + k*512 + seg*128;
            const double* xr = s_x + seg*128;
            double s = 0.0;
            for (int c = 0; c < 128; ++c) {
                double dd = xr[c] - (double)cr[c];
                s = fma(dd, dd, s);
            }
            s_d[seg*64 + k] = s;
        }
        __syncthreads();

        if (tid < 64) {
            double dv = s_d[tid] + s_d[64+tid] + s_d[128+tid] + s_d[192+tid];
            int kk2 = tid;
            #pragma unroll
            for (int off = 32; off > 0; off >>= 1) {
                double od = __shfl_xor(dv, off);
                int    ok = __shfl_xor(kk2, off);
                if (od < dv || (od == dv && ok < kk2)) { dv = od; kk2 = ok; }
            }
            if (tid == 0) qidx[row] = kk2;
        }
        __syncthreads();
    }
}

// ---------------------------------------------------------------------------
// finalize: loss1 = sum (hist - vq_x)^2, vq_mean
// ---------------------------------------------------------------------------
__global__ __launch_bounds__(256)
void finalize_k(const float* __restrict__ vqx, const int* __restrict__ ids,
                const int* __restrict__ masks, const float* __restrict__ table,
                float* __restrict__ out_mean, float* __restrict__ acc)
{
    const int b = blockIdx.x;
    const int tid = threadIdx.x;
    const float* vb = vqx + (size_t)b * 6400;

    float part = 0.f;
    for (int i = tid; i < 6400; i += 256) {
        int l = i >> 6, d = i & 63;
        int id = ids[b * L + l];
        float m = (masks[b * L + l] >= 1) ? 1.f : 0.f;
        float h = table[(size_t)id * 64 + d] * m;
        float diff = h - vb[i];
        part = fmaf(diff, diff, part);
    }
    __shared__ float s_red[4];
    #pragma unroll
    for (int off = 32; off > 0; off >>= 1) part += __shfl_down(part, off);
    if ((tid & 63) == 0) s_red[tid >> 6] = part;
    __syncthreads();
    if (tid == 0) atomicAdd(acc + 0, s_red[0] + s_red[1] + s_red[2] + s_red[3]);

    if (tid < 64) {
        float msum = 0.f;
        for (int l = 0; l < L; ++l) msum += (masks[b * L + l] >= 1) ? 1.f : 0.f;
        float s = 0.f;
        for (int l = 0; l < L; ++l) s += vb[l * 64 + tid];
        out_mean[b * 64 + tid] = s / msum;
    }
}

__global__ void loss_k(const float* __restrict__ acc, float* __restrict__ out_loss)
{
    float l1 = acc[0] / 13107200.f;
    float l2 = acc[1] / 51380224.f;
    out_loss[0] = l1 + l2 + 0.25f * l2;
}

// ---------------------------------------------------------------------------
extern "C" void kernel_launch(void* const* d_in, const int* in_sizes, int n_in,
                              void* d_out, int out_size, void* d_ws, size_t ws_size,
                              hipStream_t stream)
{
    const int*   ids   = (const int*)d_in[0];
    const int*   masks = (const int*)d_in[1];
    const float* table = (const float*)d_in[2];
    const float* book  = (const float*)d_in[3];
    const float* e_w1  = (const float*)d_in[4];
    const float* e_b1  = (const float*)d_in[5];
    const float* e_g1  = (const float*)d_in[6];
    const float* e_be1 = (const float*)d_in[7];
    const float* e_w2  = (const float*)d_in[8];
    const float* e_b2  = (const float*)d_in[9];
    const float* e_g2  = (const float*)d_in[10];
    const float* e_be2 = (const float*)d_in[11];
    const float* e_w3  = (const float*)d_in[12];
    const float* e_b3  = (const float*)d_in[13];
    const float* d_w1  = (const float*)d_in[14];
    const float* d_b1  = (const float*)d_in[15];
    const float* d_g1  = (const float*)d_in[16];
    const float* d_be1 = (const float*)d_in[17];
    const float* d_w2  = (const float*)d_in[18];
    const float* d_b2  = (const float*)d_in[19];
    const float* d_g2  = (const float*)d_in[20];
    const float* d_be2 = (const float*)d_in[21];
    const float* d_w3  = (const float*)d_in[22];
    const float* d_b3  = (const float*)d_in[23];

    float* ws  = (float*)d_ws;
    float* A1  = ws + R0_OFF;            // [B,9,9,128]
    float* A2  = ws + R1_OFF;            // [B,8,8,256]
    float* XE  = ws + R0_OFF;            // [B,7,7,512]
    float* G1  = ws + R1_OFF;            // [B,8,8,256]
    float* G2  = ws + R0_OFF;            // [B,9,9,128]
    int*   IDX = (int*)(ws + IDX_OFF);
    float* UBT = ws + UBT_OFF;
    float* CBN = ws + CBN_OFF;
    int*   CNT = (int*)(ws + CNT_OFF);
    float* ACC = ws + ACC_OFF;
    int*   WL  = (int*)(ws + WL_OFF);

    float* out_mean = (float*)d_out;
    float* out_vqx  = (float*)d_out + (size_t)B * 64;
    float* out_loss = (float*)d_out + (size_t)B * 64 + (size_t)B * L * 64;

    prep_k<<<1, 256, 0, stream>>>(book, UBT, CBN, ACC, CNT);

    // encoder (f32)
    convf_k<10,10, 64,128,0,1,true , 8,1, 64><<<B,   256,0,stream>>>(nullptr, ids, masks, table, nullptr, nullptr, e_w1, e_b1, e_g1, e_be1, A1);
    convf_k< 9, 9,128,256,0,0,true , 8,1, 64><<<B,   256,0,stream>>>(A1, nullptr, nullptr, nullptr, nullptr, nullptr, e_w2, e_b2, e_g2, e_be2, A2);
    convf_k< 8, 8,256,512,0,0,false,16,2,128><<<B*2, 256,0,stream>>>(A2, nullptr, nullptr, nullptr, nullptr, nullptr, e_w3, e_b3, nullptr, nullptr, XE);

    // codebook NN (f32 + margin flag) then f64 re-verify of flagged rows
    nn_k<<<6272, 256, 0, stream>>>(XE, UBT, CBN, IDX, ACC, CNT, WL);
    recompute_k<<<512, 256, 0, stream>>>(WL, CNT, ids, masks, table, book,
                                         e_w1, e_b1, e_g1, e_be1,
                                         e_w2, e_b2, e_g2, e_be2,
                                         e_w3, e_b3, IDX);

    // decoder (f32; conv_transpose == conv pad=1, unflipped kernel)
    convf_k< 7, 7,512,256,1,2,true ,16,1,128><<<B,   256,0,stream>>>(nullptr, nullptr, nullptr, nullptr, IDX, book, d_w1, d_b1, d_g1, d_be1, G1);
    convf_k< 8, 8,256,128,1,0,true , 8,1,128><<<B,   256,0,stream>>>(G1, nullptr, nullptr, nullptr, nullptr, nullptr, d_w2, d_b2, d_g2, d_be2, G2);
    convf_k< 9, 9,128, 64,1,0,false, 8,1, 64><<<B,   256,0,stream>>>(G2, nullptr, nullptr, nullptr, nullptr, nullptr, d_w3, d_b3, nullptr, nullptr, out_vqx);

    // vq_mean + loss1, then scalar loss
    finalize_k<<<B, 256, 0, stream>>>(out_vqx, ids, masks, table, out_mean, ACC);
    loss_k<<<1, 1, 0, stream>>>(ACC, out_loss);
}

// Round 4
// 2285.693 us; speedup vs baseline: 4.3954x; 3.0607x over previous
//
#include <hip/hip_runtime.h>
#include <hip/hip_bf16.h>
#include <cstdint>
#include <cstddef>

// ---------------------------------------------------------------------------
// VQ-VAE forward (B=2048, L=100, D=64, K=64, CB=512) — MFMA edition.
// Encoder convs: split-bf16 (hi+lo) MFMA, 3 passes -> ~f32 accuracy.
// Decoder convs: plain bf16 MFMA (threshold 0.1975 >> bf16 conv noise).
// Argmin exactness: margin 0.1 flag -> f64 full recompute of flagged rows.
// ---------------------------------------------------------------------------

typedef __attribute__((ext_vector_type(8))) short short8v;   // 8 bf16 (4 VGPR)
typedef __attribute__((ext_vector_type(4))) float f32x4;

constexpr int B  = 2048;
constexpr int L  = 100;
constexpr int K  = 64;
constexpr int CB = 512;
#define MARGIN 0.1f

// workspace layout (float offsets), all multiples of 16:
//  R0: A1 [B*81*128] -> XENC [B*49*512] -> G2 [B*81*128]
//  R1: A2 [B*64*256] -> G1 [B*64*256]
constexpr size_t R0_OFF  = 0;
constexpr size_t R0_SZ   = 51380224;
constexpr size_t R1_OFF  = 51380224;
constexpr size_t R1_SZ   = 33554432;
constexpr size_t IDX_OFF = 84934656;   // 2048*49 ints
constexpr size_t UBT_OFF = 85035008;   // 512*64 transposed codebook
constexpr size_t CBN_OFF = 85067776;   // 64 code norms
constexpr size_t CNT_OFF = 85067840;   // worklist count (16 reserved)
constexpr size_t ACC_OFF = 85067856;   // 2 loss accumulators (16 reserved)
constexpr size_t WL_OFF  = 85067872;   // up to 100352 ints
constexpr size_t WB_OFF  = 85168224;   // bf16 weight region (ushorts)

// bf16 weight sub-offsets (ushort units), layout [4][OC][IC]
constexpr size_t EW1H=0,       EW1L=32768;
constexpr size_t EW2H=65536,   EW2L=196608;
constexpr size_t EW3H=327680,  EW3L=851968;
constexpr size_t DW1H=1376256, DW2H=1900544, DW3H=2031616;

__device__ inline ushort bf16_hi(float f){ __hip_bfloat16 h=__float2bfloat16(f); return *(ushort*)&h; }
__device__ inline float  bf16_tof(ushort u){ __hip_bfloat16 h; *(ushort*)&h=u; return __bfloat162float(h); }

// ---------------------------------------------------------------------------
// weight prep: w[2,2,IC,OC] f32 -> Wt[kk][oc][ic] bf16 hi (+lo for encoder)
// ---------------------------------------------------------------------------
__device__ void wtrans(const float* __restrict__ w, int IC, int OC,
                       ushort* __restrict__ hi, ushort* __restrict__ lo,
                       int gid, int gsz)
{
    int tot = 4*IC*OC;
    for (int i = gid; i < tot; i += gsz) {
        int kk = i/(IC*OC), r = i - kk*(IC*OC), ic = r/OC, oc = r - ic*OC;
        float v = w[i];
        ushort h = bf16_hi(v);
        size_t dst = ((size_t)kk*OC + oc)*IC + ic;
        hi[dst] = h;
        if (lo) lo[dst] = bf16_hi(v - bf16_tof(h));
    }
}

__global__ __launch_bounds__(256)
void wprep_k(const float* e1, const float* e2, const float* e3,
             const float* d1, const float* d2, const float* d3,
             ushort* wb)
{
    int gid = blockIdx.x*256 + threadIdx.x, gsz = gridDim.x*256;
    wtrans(e1,  64, 128, wb+EW1H, wb+EW1L, gid, gsz);
    wtrans(e2, 128, 256, wb+EW2H, wb+EW2L, gid, gsz);
    wtrans(e3, 256, 512, wb+EW3H, wb+EW3L, gid, gsz);
    wtrans(d1, 512, 256, wb+DW1H, nullptr, gid, gsz);
    wtrans(d2, 256, 128, wb+DW2H, nullptr, gid, gsz);
    wtrans(d3, 128,  64, wb+DW3H, nullptr, gid, gsz);
}

// ---------------------------------------------------------------------------
// MFMA 2x2 conv. One sample per block, 4 waves split OC.
// Input tile staged in LDS as bf16 (hi [+lo]), XOR-swizzled (row&7)<<4.
// A-frag: lane&15=row(pos), k=(lane>>4)*8+j (ds_read_b128).
// B-frag: lane&15=col(oc), 16B GLOBAL load from pre-transposed Wt[kk][oc][ic].
// C:      col=lane&15, row=(lane>>4)*4+j.
// MODE 0: activations; 1: embedding gather+mask; 2: codebook gather.
// ---------------------------------------------------------------------------
template<int IH,int IW,int IC,int OC,int PAD,int MODE,bool BN_,bool SPLIT,int ICC>
__global__ __launch_bounds__(256)
void mconv_k(const float* __restrict__ in, const int* __restrict__ ids,
             const int* __restrict__ masks, const float* __restrict__ table,
             const int* __restrict__ qidx, const float* __restrict__ book,
             const ushort* __restrict__ wt_hi, const ushort* __restrict__ wt_lo,
             const float* __restrict__ bias, const float* __restrict__ gamma,
             const float* __restrict__ beta, float* __restrict__ out)
{
    constexpr int OH=IH+2*PAD-1, OW=IW+2*PAD-1, NPOS=OH*OW, IHW=IH*IW;
    constexpr int MT=(NPOS+15)/16;          // 16-row M tiles (padded)
    constexpr int NPW=OC/4, NT=NPW/16;      // per-wave N columns / 16-col tiles
    constexpr int NCH=IC/ICC, KS=ICC/32;    // ic chunks, k-steps per chunk
    constexpr int CP=SPLIT?2:1;
    constexpr int AROWS=IHW+1;              // +1 zero row for invalid taps
    constexpr int RB=ICC*2;                 // LDS row bytes

    __shared__ ushort s_a[CP*AROWS*ICC];

    const int b=blockIdx.x, tid=threadIdx.x;
    const int lane=tid&63, wv=tid>>6;
    const int n0=wv*NPW;
    const int l15=lane&15, lq=lane>>4;

    f32x4 acc[MT][NT];
    #pragma unroll
    for(int m=0;m<MT;++m)
        #pragma unroll
        for(int n=0;n<NT;++n) acc[m][n]=(f32x4)0.0f;

    char* sb=(char*)s_a;

    for(int ch=0; ch<NCH; ++ch){
        const int ic0=ch*ICC;
        // zero row (index IHW)
        for(int g=tid; g<CP*(ICC/8); g+=256){
            int cp=g/(ICC/8), gg=g-cp*(ICC/8);
            int off=cp*AROWS*RB + IHW*RB + ((gg*16) ^ ((IHW&7)<<4));
            *(uint4*)(sb+off)=make_uint4(0,0,0,0);
        }
        // stage input rows (f32 -> bf16 hi/lo, swizzled ds_write 16B)
        for(int i=tid; i<IHW*(ICC/8); i+=256){
            int row=i/(ICC/8), g=i-row*(ICC/8);
            const float* src; float msc=1.f;
            if constexpr(MODE==0){
                src = in + ((size_t)b*IHW+row)*IC + ic0 + g*8;
            } else if constexpr(MODE==1){
                int id=ids[b*L+row];
                msc=(masks[b*L+row]>=1)?1.f:0.f;
                src = table + (size_t)id*64 + ic0 + g*8;
            } else {
                int kq=qidx[b*49+row];
                src = book + (size_t)kq*512 + ic0 + g*8;
            }
            float4 v0=*(const float4*)src;
            float4 v1=*(const float4*)(src+4);
            float vv[8]={v0.x*msc,v0.y*msc,v0.z*msc,v0.w*msc,
                         v1.x*msc,v1.y*msc,v1.z*msc,v1.w*msc};
            ushort hh[8];
            #pragma unroll
            for(int j=0;j<8;++j) hh[j]=bf16_hi(vv[j]);
            int boff = row*RB + ((g*16) ^ ((row&7)<<4));
            *(uint4*)(sb+boff)=*(uint4*)hh;
            if constexpr(SPLIT){
                ushort ll[8];
                #pragma unroll
                for(int j=0;j<8;++j) ll[j]=bf16_hi(vv[j]-bf16_tof(hh[j]));
                *(uint4*)(sb+AROWS*RB+boff)=*(uint4*)ll;
            }
        }
        __syncthreads();

        #pragma unroll
        for(int kk=0;kk<4;++kk){
            const int ky=kk>>1, kx=kk&1;
            int arow[MT];
            #pragma unroll
            for(int m=0;m<MT;++m){
                int p=m*16+l15;
                int py=p/OW, px=p-py*OW;
                int ty=py+ky-PAD, tx=px+kx-PAD;
                bool ok=(p<NPOS)&&(ty>=0)&&(ty<IH)&&(tx>=0)&&(tx<IW);
                arow[m]= ok ? ty*IW+tx : IHW;
            }
            for(int ks=0;ks<KS;++ks){
                const int kb=ks*64+lq*16;
                short8v ah[MT]; short8v al[SPLIT?MT:1];
                #pragma unroll
                for(int m=0;m<MT;++m){
                    int off=arow[m]*RB + (kb ^ ((arow[m]&7)<<4));
                    ah[m]=*(const short8v*)(sb+off);
                    if constexpr(SPLIT) al[m]=*(const short8v*)(sb+AROWS*RB+off);
                }
                #pragma unroll
                for(int n=0;n<NT;++n){
                    int col=n0+n*16+l15;
                    size_t widx=((size_t)kk*OC+col)*IC + ic0 + ks*32 + lq*8;
                    short8v bh=*(const short8v*)(wt_hi+widx);
                    if constexpr(SPLIT){
                        short8v bl=*(const short8v*)(wt_lo+widx);
                        #pragma unroll
                        for(int m=0;m<MT;++m){
                            acc[m][n]=__builtin_amdgcn_mfma_f32_16x16x32_bf16(ah[m],bh,acc[m][n],0,0,0);
                            acc[m][n]=__builtin_amdgcn_mfma_f32_16x16x32_bf16(ah[m],bl,acc[m][n],0,0,0);
                            acc[m][n]=__builtin_amdgcn_mfma_f32_16x16x32_bf16(al[m],bh,acc[m][n],0,0,0);
                        }
                    } else {
                        #pragma unroll
                        for(int m=0;m<MT;++m)
                            acc[m][n]=__builtin_amdgcn_mfma_f32_16x16x32_bf16(ah[m],bh,acc[m][n],0,0,0);
                    }
                }
            }
        }
        __syncthreads();
    }

    const float rs=(float)(1.0/sqrt(1.0+1e-3));
    #pragma unroll
    for(int n=0;n<NT;++n){
        int col=n0+n*16+l15;
        float bi=bias[col];
        float gsc=0.f, bt=0.f;
        if constexpr(BN_){ gsc=gamma[col]*rs; bt=beta[col]; }
        #pragma unroll
        for(int m=0;m<MT;++m){
            #pragma unroll
            for(int j=0;j<4;++j){
                int p=m*16+lq*4+j;
                if(p<NPOS){
                    float v=acc[m][n][j]+bi;
                    if constexpr(BN_) v=fmaxf(fmaf(v,gsc,bt),0.f);
                    out[((size_t)b*NPOS+p)*OC+col]=v;
                }
            }
        }
    }
}

// ---------------------------------------------------------------------------
// prep: transpose codebook, code norms, zero accumulators + worklist count
// ---------------------------------------------------------------------------
__global__ __launch_bounds__(256)
void prep_k(const float* __restrict__ book, float* __restrict__ ubt,
            float* __restrict__ cbn, float* __restrict__ acc, int* __restrict__ cnt)
{
    for (int i = threadIdx.x; i < K * CB; i += 256) {
        int k = i >> 9, c = i & 511;
        ubt[c * 64 + k] = book[i];
    }
    if (threadIdx.x < 64) {
        const float* r = book + threadIdx.x * 512;
        float s = 0.f;
        for (int c = 0; c < 512; ++c) s = fmaf(r[c], r[c], s);
        cbn[threadIdx.x] = s;
    }
    if (threadIdx.x < 2) acc[threadIdx.x] = 0.f;
    if (threadIdx.x == 0) *cnt = 0;
}

// ---------------------------------------------------------------------------
// NN search (f32): wave per 4 rows, lane = code. best + runner-up;
// gap <= MARGIN -> worklist for f64 re-verification. loss2 accumulated.
// ---------------------------------------------------------------------------
__global__ __launch_bounds__(256)
void nn_k(const float* __restrict__ xenc, const float* __restrict__ ubt,
          const float* __restrict__ cbn, int* __restrict__ qidx,
          float* __restrict__ acc, int* __restrict__ cnt, int* __restrict__ wl)
{
    const int lane = threadIdx.x & 63;
    const int wave = threadIdx.x >> 6;
    const int wid  = blockIdx.x * 4 + wave;
    const int row0 = wid * 4;
    const float* x0 = xenc + (size_t)row0 * 512;

    float dot[4] = {0.f,0.f,0.f,0.f};
    float xn[4]  = {0.f,0.f,0.f,0.f};
    for (int c = 0; c < 512; ++c) {
        float ub = ubt[c * 64 + lane];
        float a0 = x0[c], a1 = x0[512+c], a2 = x0[1024+c], a3 = x0[1536+c];
        dot[0] = fmaf(a0, ub, dot[0]);  xn[0] = fmaf(a0, a0, xn[0]);
        dot[1] = fmaf(a1, ub, dot[1]);  xn[1] = fmaf(a1, a1, xn[1]);
        dot[2] = fmaf(a2, ub, dot[2]);  xn[2] = fmaf(a2, a2, xn[2]);
        dot[3] = fmaf(a3, ub, dot[3]);  xn[3] = fmaf(a3, a3, xn[3]);
    }

    float l2sum = 0.f;
    #pragma unroll
    for (int j = 0; j < 4; ++j) {
        float d1 = cbn[lane] - 2.f * dot[j];
        int   k1 = lane;
        float d2 = 3.4e38f;
        #pragma unroll
        for (int off = 32; off > 0; off >>= 1) {
            float od1 = __shfl_xor(d1, off);
            int   ok1 = __shfl_xor(k1, off);
            float od2 = __shfl_xor(d2, off);
            if (od1 < d1 || (od1 == d1 && ok1 < k1)) {
                d2 = fminf(d1, od2); d1 = od1; k1 = ok1;
            } else {
                d2 = fminf(d2, od1);
            }
        }
        if (lane == 0) {
            qidx[row0 + j] = k1;
            if (d2 - d1 <= MARGIN) { int t = atomicAdd(cnt, 1); wl[t] = row0 + j; }
            l2sum += d1 + xn[j];
        }
    }
    if (lane == 0) atomicAdd(acc + 1, l2sum);
}

// ---------------------------------------------------------------------------
// f64 re-verification of flagged rows (full receptive field from scratch).
// ---------------------------------------------------------------------------
__global__ __launch_bounds__(256)
void recompute_k(const int* __restrict__ wl, const int* __restrict__ cnt,
                 const int* __restrict__ ids, const int* __restrict__ masks,
                 const float* __restrict__ table, const float* __restrict__ book,
                 const float* __restrict__ e_w1, const float* __restrict__ e_b1,
                 const float* __restrict__ e_g1, const float* __restrict__ e_be1,
                 const float* __restrict__ e_w2, const float* __restrict__ e_b2,
                 const float* __restrict__ e_g2, const float* __restrict__ e_be2,
                 const float* __restrict__ e_w3, const float* __restrict__ e_b3,
                 int* __restrict__ qidx)
{
    __shared__ double s_h[16*64];
    __shared__ double s_a1[9*128];
    __shared__ double s_a2[4*256];
    __shared__ double s_x[512];
    __shared__ double s_d[256];

    const int tid = threadIdx.x;
    const double rs = 1.0 / sqrt(1.0 + 1e-3);
    const int n = *cnt;

    for (int wi = blockIdx.x; wi < n; wi += gridDim.x) {
        const int row = wl[wi];
        const int b = row / 49, p = row % 49;
        const int py = p / 7, px = p % 7;

        for (int i = tid; i < 16*64; i += 256) {
            int cell = i >> 6, d = i & 63;
            int l = (py + (cell >> 2)) * 10 + (px + (cell & 3));
            int id = ids[b*100 + l];
            double m = (masks[b*100 + l] >= 1) ? 1.0 : 0.0;
            s_h[i] = (double)table[(size_t)id*64 + d] * m;
        }
        __syncthreads();

        for (int i = tid; i < 9*128; i += 256) {
            int cell = i >> 7, oc = i & 127;
            int ry = cell / 3, rx = cell % 3;
            double s = 0.0;
            #pragma unroll
            for (int kk = 0; kk < 4; ++kk) {
                int icell = (ry + (kk>>1))*4 + (rx + (kk&1));
                const double* hh = s_h + icell*64;
                const float* ww = e_w1 + (kk*64)*128 + oc;
                for (int ic = 0; ic < 64; ++ic)
                    s = fma(hh[ic], (double)ww[ic*128], s);
            }
            s += (double)e_b1[oc];
            s = s * ((double)e_g1[oc] * rs) + (double)e_be1[oc];
            s_a1[i] = s > 0.0 ? s : 0.0;
        }
        __syncthreads();

        for (int i = tid; i < 4*256; i += 256) {
            int cell = i >> 8, oc = i & 255;
            int qy = cell >> 1, qx = cell & 1;
            double s = 0.0;
            #pragma unroll
            for (int kk = 0; kk < 4; ++kk) {
                int icell = (qy + (kk>>1))*3 + (qx + (kk&1));
                const double* aa = s_a1 + icell*128;
                const float* ww = e_w2 + (kk*128)*256 + oc;
                for (int ic = 0; ic < 128; ++ic)
                    s = fma(aa[ic], (double)ww[ic*256], s);
            }
            s += (double)e_b2[oc];
            s = s * ((double)e_g2[oc] * rs) + (double)e_be2[oc];
            s_a2[i] = s > 0.0 ? s : 0.0;
        }
        __syncthreads();

        for (int i = tid; i < 512; i += 256) {
            double s = 0.0;
            #pragma unroll
            for (int kk = 0; kk < 4; ++kk) {
                const double* aa = s_a2 + kk*256;
                const float* ww = e_w3 + (kk*256)*512 + i;
                for (int ic = 0; ic < 256; ++ic)
                    s = fma(aa[ic], (double)ww[ic*512], s);
            }
            s_x[i] = s + (double)e_b3[i];
        }
        __syncthreads();

        {
            int k = tid & 63, seg = tid >> 6;
            const float* cr = book + k*512 + seg*128;
            const double* xr = s_x + seg*128;
            double s = 0.0;
            for (int c = 0; c < 128; ++c) {
                double dd = xr[c] - (double)cr[c];
                s = fma(dd, dd, s);
            }
            s_d[seg*64 + k] = s;
        }
        __syncthreads();

        if (tid < 64) {
            double dv = s_d[tid] + s_d[64+tid] + s_d[128+tid] + s_d[192+tid];
            int kk2 = tid;
            #pragma unroll
            for (int off = 32; off > 0; off >>= 1) {
                double od = __shfl_xor(dv, off);
                int    ok = __shfl_xor(kk2, off);
                if (od < dv || (od == dv && ok < kk2)) { dv = od; kk2 = ok; }
            }
            if (tid == 0) qidx[row] = kk2;
        }
        __syncthreads();
    }
}

// ---------------------------------------------------------------------------
// finalize: loss1 = sum (hist - vq_x)^2, vq_mean
// ---------------------------------------------------------------------------
__global__ __launch_bounds__(256)
void finalize_k(const float* __restrict__ vqx, const int* __restrict__ ids,
                const int* __restrict__ masks, const float* __restrict__ table,
                float* __restrict__ out_mean, float* __restrict__ acc)
{
    const int b = blockIdx.x;
    const int tid = threadIdx.x;
    const float* vb = vqx + (size_t)b * 6400;

    float part = 0.f;
    for (int i = tid; i < 6400; i += 256) {
        int l = i >> 6, d = i & 63;
        int id = ids[b * L + l];
        float m = (masks[b * L + l] >= 1) ? 1.f : 0.f;
        float h = table[(size_t)id * 64 + d] * m;
        float diff = h - vb[i];
        part = fmaf(diff, diff, part);
    }
    __shared__ float s_red[4];
    #pragma unroll
    for (int off = 32; off > 0; off >>= 1) part += __shfl_down(part, off);
    if ((tid & 63) == 0) s_red[tid >> 6] = part;
    __syncthreads();
    if (tid == 0) atomicAdd(acc + 0, s_red[0] + s_red[1] + s_red[2] + s_red[3]);

    if (tid < 64) {
        float msum = 0.f;
        for (int l = 0; l < L; ++l) msum += (masks[b * L + l] >= 1) ? 1.f : 0.f;
        float s = 0.f;
        for (int l = 0; l < L; ++l) s += vb[l * 64 + tid];
        out_mean[b * 64 + tid] = s / msum;
    }
}

__global__ void loss_k(const float* __restrict__ acc, float* __restrict__ out_loss)
{
    float l1 = acc[0] / 13107200.f;
    float l2 = acc[1] / 51380224.f;
    out_loss[0] = l1 + l2 + 0.25f * l2;
}

// ---------------------------------------------------------------------------
extern "C" void kernel_launch(void* const* d_in, const int* in_sizes, int n_in,
                              void* d_out, int out_size, void* d_ws, size_t ws_size,
                              hipStream_t stream)
{
    const int*   ids   = (const int*)d_in[0];
    const int*   masks = (const int*)d_in[1];
    const float* table = (const float*)d_in[2];
    const float* book  = (const float*)d_in[3];
    const float* e_w1  = (const float*)d_in[4];
    const float* e_b1  = (const float*)d_in[5];
    const float* e_g1  = (const float*)d_in[6];
    const float* e_be1 = (const float*)d_in[7];
    const float* e_w2  = (const float*)d_in[8];
    const float* e_b2  = (const float*)d_in[9];
    const float* e_g2  = (const float*)d_in[10];
    const float* e_be2 = (const float*)d_in[11];
    const float* e_w3  = (const float*)d_in[12];
    const float* e_b3  = (const float*)d_in[13];
    const float* d_w1  = (const float*)d_in[14];
    const float* d_b1  = (const float*)d_in[15];
    const float* d_g1  = (const float*)d_in[16];
    const float* d_be1 = (const float*)d_in[17];
    const float* d_w2  = (const float*)d_in[18];
    const float* d_b2  = (const float*)d_in[19];
    const float* d_g2  = (const float*)d_in[20];
    const float* d_be2 = (const float*)d_in[21];
    const float* d_w3  = (const float*)d_in[22];
    const float* d_b3  = (const float*)d_in[23];

    float*  ws  = (float*)d_ws;
    float*  A1  = ws + R0_OFF;            // [B,9,9,128]
    float*  A2  = ws + R1_OFF;            // [B,8,8,256]
    float*  XE  = ws + R0_OFF;            // [B,7,7,512]
    float*  G1  = ws + R1_OFF;            // [B,8,8,256]
    float*  G2  = ws + R0_OFF;            // [B,9,9,128]
    int*    IDX = (int*)(ws + IDX_OFF);
    float*  UBT = ws + UBT_OFF;
    float*  CBN = ws + CBN_OFF;
    int*    CNT = (int*)(ws + CNT_OFF);
    float*  ACC = ws + ACC_OFF;
    int*    WL  = (int*)(ws + WL_OFF);
    ushort* WB  = (ushort*)(ws + WB_OFF);

    float* out_mean = (float*)d_out;
    float* out_vqx  = (float*)d_out + (size_t)B * 64;
    float* out_loss = (float*)d_out + (size_t)B * 64 + (size_t)B * L * 64;

    prep_k<<<1, 256, 0, stream>>>(book, UBT, CBN, ACC, CNT);
    wprep_k<<<512, 256, 0, stream>>>(e_w1, e_w2, e_w3, d_w1, d_w2, d_w3, WB);

    // encoder (split-bf16 MFMA)
    mconv_k<10,10, 64,128,0,1,true ,true , 64><<<B,256,0,stream>>>(
        nullptr, ids, masks, table, nullptr, nullptr, WB+EW1H, WB+EW1L, e_b1, e_g1, e_be1, A1);
    mconv_k< 9, 9,128,256,0,0,true ,true ,128><<<B,256,0,stream>>>(
        A1, nullptr, nullptr, nullptr, nullptr, nullptr, WB+EW2H, WB+EW2L, e_b2, e_g2, e_be2, A2);
    mconv_k< 8, 8,256,512,0,0,false,true ,128><<<B,256,0,stream>>>(
        A2, nullptr, nullptr, nullptr, nullptr, nullptr, WB+EW3H, WB+EW3L, e_b3, nullptr, nullptr, XE);

    // codebook NN (f32 + margin flag) then f64 re-verify of flagged rows
    nn_k<<<6272, 256, 0, stream>>>(XE, UBT, CBN, IDX, ACC, CNT, WL);
    recompute_k<<<512, 256, 0, stream>>>(WL, CNT, ids, masks, table, book,
                                         e_w1, e_b1, e_g1, e_be1,
                                         e_w2, e_b2, e_g2, e_be2,
                                         e_w3, e_b3, IDX);

    // decoder (plain bf16 MFMA; conv_transpose == conv pad=1, same weight order)
    mconv_k< 7, 7,512,256,1,2,true ,false,128><<<B,256,0,stream>>>(
        nullptr, nullptr, nullptr, nullptr, IDX, book, WB+DW1H, nullptr, d_b1, d_g1, d_be1, G1);
    mconv_k< 8, 8,256,128,1,0,true ,false,128><<<B,256,0,stream>>>(
        G1, nullptr, nullptr, nullptr, nullptr, nullptr, WB+DW2H, nullptr, d_b2, d_g2, d_be2, G2);
    mconv_k< 9, 9,128, 64,1,0,false,false,128><<<B,256,0,stream>>>(
        G2, nullptr, nullptr, nullptr, nullptr, nullptr, WB+DW3H, nullptr, d_b3, nullptr, nullptr, out_vqx);

    // vq_mean + loss1, then scalar loss
    finalize_k<<<B, 256, 0, stream>>>(out_vqx, ids, masks, table, out_mean, ACC);
    loss_k<<<1, 1, 0, stream>>>(ACC, out_loss);
}